// Round 10
// baseline (231.518 us; speedup 1.0000x reference)
//
#include <hip/hip_runtime.h>
#include <math.h>

constexpr int KK = 2;
constexpr int HH = 4;
constexpr int NN = 4096;
constexpr int DD = 64;
constexpr int OO = 64;
constexpr int NU = 4000;
constexpr int CC = 2;
constexpr float LOG2E = 1.44269504088896340736f;

typedef float vf4 __attribute__((ext_vector_type(4)));
typedef float vf2 __attribute__((ext_vector_type(2)));

__device__ __forceinline__ float fexp2(float x) {
#if __has_builtin(__builtin_amdgcn_exp2f)
  return __builtin_amdgcn_exp2f(x);
#else
  return exp2f(x);
#endif
}
__device__ __forceinline__ float frcp(float x) {
#if __has_builtin(__builtin_amdgcn_rcpf)
  return __builtin_amdgcn_rcpf(x);
#else
  return 1.0f / x;
#endif
}
__device__ __forceinline__ float ftanh(float x) {
  float e = fexp2(x * (2.0f * LOG2E));
  return 1.0f - 2.0f * frcp(e + 1.0f);
}

// ---------------------------------------------------------------------------
// Phase 1: per (k,h): hp = h @ w; per node i (SoA planes, factorized):
//   srcAA[kh][i] = {2^src', 2^(0.2 src')}
//   Bp[kh][j]=2^dst', B5p[kh][j]=2^(0.2 dst'), g0p/g1p[kh][j]=hp_j.fc_w_c
// exp2(leaky(s)) == max(A*B, A5*B5)  (exact; validated R9).
// ---------------------------------------------------------------------------
__global__ __launch_bounds__(256) void gat_phase1(
    const float* __restrict__ hsrc, const float* __restrict__ w,
    const float* __restrict__ a_src, const float* __restrict__ a_dst,
    const float* __restrict__ fc_w,
    float* __restrict__ srcAA, float* __restrict__ Bp,
    float* __restrict__ B5p, float* __restrict__ g0p,
    float* __restrict__ g1p) {
  const int kh = blockIdx.y;  // 0..7
  const int k = kh >> 2;
  const int i0 = blockIdx.x * 64;
  const int tid = threadIdx.x;

  __shared__ float h_s[DD][68];
  __shared__ float w_s[DD][OO];
  __shared__ float part[4][64][17];  // [val][row][og], padded

  {
    const vf4* wp = (const vf4*)(w + (size_t)kh * DD * OO);
    vf4* ws4 = (vf4*)w_s;
    for (int t = tid; t < DD * OO / 4; t += 256) ws4[t] = wp[t];
  }
  for (int t = tid; t < 1024; t += 256) {
    const int row = t >> 4;
    const int f4 = (t & 15) * 4;
    vf4 v = *(const vf4*)(hsrc + (size_t)(i0 + row) * DD + f4);
    h_s[f4 + 0][row] = v.x;
    h_s[f4 + 1][row] = v.y;
    h_s[f4 + 2][row] = v.z;
    h_s[f4 + 3][row] = v.w;
  }
  __syncthreads();

  const int og = tid & 15;
  const int rg = tid >> 4;
  const int o0 = og * 4;
  const int r0 = rg * 4;

  float hp[4][4];
#pragma unroll
  for (int j = 0; j < 4; ++j)
#pragma unroll
    for (int u = 0; u < 4; ++u) hp[j][u] = 0.0f;

#pragma unroll 8
  for (int f = 0; f < DD; ++f) {
    vf4 hv = *(const vf4*)&h_s[f][r0];
    vf4 wv = *(const vf4*)&w_s[f][o0];
    hp[0][0] = fmaf(hv.x, wv.x, hp[0][0]);
    hp[0][1] = fmaf(hv.x, wv.y, hp[0][1]);
    hp[0][2] = fmaf(hv.x, wv.z, hp[0][2]);
    hp[0][3] = fmaf(hv.x, wv.w, hp[0][3]);
    hp[1][0] = fmaf(hv.y, wv.x, hp[1][0]);
    hp[1][1] = fmaf(hv.y, wv.y, hp[1][1]);
    hp[1][2] = fmaf(hv.y, wv.z, hp[1][2]);
    hp[1][3] = fmaf(hv.y, wv.w, hp[1][3]);
    hp[2][0] = fmaf(hv.z, wv.x, hp[2][0]);
    hp[2][1] = fmaf(hv.z, wv.y, hp[2][1]);
    hp[2][2] = fmaf(hv.z, wv.z, hp[2][2]);
    hp[2][3] = fmaf(hv.z, wv.w, hp[2][3]);
    hp[3][0] = fmaf(hv.w, wv.x, hp[3][0]);
    hp[3][1] = fmaf(hv.w, wv.y, hp[3][1]);
    hp[3][2] = fmaf(hv.w, wv.z, hp[3][2]);
    hp[3][3] = fmaf(hv.w, wv.w, hp[3][3]);
  }

  float as[4], ad[4], f0[4], f1[4];
#pragma unroll
  for (int u = 0; u < 4; ++u) {
    as[u] = a_src[kh * OO + o0 + u];
    ad[u] = a_dst[kh * OO + o0 + u];
    f0[u] = fc_w[0 * (KK * OO) + k * OO + o0 + u];
    f1[u] = fc_w[1 * (KK * OO) + k * OO + o0 + u];
  }

#pragma unroll
  for (int j = 0; j < 4; ++j) {
    float sp = 0.0f, dp = 0.0f, g0 = 0.0f, g1 = 0.0f;
#pragma unroll
    for (int u = 0; u < 4; ++u) {
      float v = hp[j][u];
      float t = ftanh(v);
      sp = fmaf(t, as[u], sp);
      dp = fmaf(t, ad[u], dp);
      g0 = fmaf(v, f0[u], g0);
      g1 = fmaf(v, f1[u], g1);
    }
    part[0][r0 + j][og] = sp;
    part[1][r0 + j][og] = dp;
    part[2][r0 + j][og] = g0;
    part[3][r0 + j][og] = g1;
  }
  __syncthreads();

  {  // thread = (row j2, val): sum 16 og-partials, transform, write out
    const int val = tid & 3;
    const int j2 = tid >> 2;
    const float* pr = &part[val][j2][0];
    vf4 s0 = *(const vf4*)(pr + 0);
    vf4 s1 = *(const vf4*)(pr + 4);
    vf4 s2 = *(const vf4*)(pr + 8);
    vf4 s3 = *(const vf4*)(pr + 12);
    vf4 t4 = s0 + s1 + s2 + s3;
    float sum = t4.x + t4.y + t4.z + t4.w;
    const size_t idx = (size_t)kh * NN + i0 + j2;
    if (val == 0) {
      float sp = sum * LOG2E;
      vf2 v = {fexp2(sp), fexp2(0.2f * sp)};
      *(vf2*)(srcAA + idx * 2) = v;
    } else if (val == 1) {
      float dp = sum * LOG2E;
      Bp[idx] = fexp2(dp);
      B5p[idx] = fexp2(0.2f * dp);
    } else if (val == 2) {
      g0p[idx] = sum;
    } else {
      g1p[idx] = sum;
    }
  }
}

// ---------------------------------------------------------------------------
// Phase 2: grid (NU/4, K), block 256 = 4 waves. Block = 4 rows x ALL j.
// Wave w owns j in [w*1024, w*1024+1024), T=4 tiles of 256 j.
// Lane = j-offset: every load (adj vf4, B/B5/g0/g1 vf4) is lane-DISTINCT
// and dense (1 KB/instr) -> zero LDS broadcast waste, no staging, no
// barriers in the hot loop. B/g planes (512 KB total) live in L2.
// A-factors are wave-uniform scalar loads.
//   e = max(A*B, A5*B5); pa = adj*e; l += pa; a_c += pa*g_c   (all pk f32)
// Reduce: fold vf2 + butterfly(48 scalars) + LDS combine + divide -> S.
// ---------------------------------------------------------------------------
__global__ __launch_bounds__(256) void gat_phase2(
    const float* __restrict__ adj, const float* __restrict__ srcAA,
    const float* __restrict__ Bp, const float* __restrict__ B5p,
    const float* __restrict__ g0p, const float* __restrict__ g1p,
    float* __restrict__ S) {
  const int k = blockIdx.y;
  const int r0 = blockIdx.x * 4;
  const int tid = threadIdx.x;
  const int wave = tid >> 6;
  const int lane = tid & 63;

  // wave-uniform A factors: A[r][h], A5[r][h] (compiler -> scalar loads)
  float A[4][4], A5[4][4];
#pragma unroll
  for (int h = 0; h < 4; ++h) {
    const float* base = srcAA + ((size_t)(k * HH + h) * NN + r0) * 2;
#pragma unroll
    for (int r = 0; r < 4; ++r) {
      A[r][h] = base[r * 2 + 0];
      A5[r][h] = base[r * 2 + 1];
    }
  }

  vf2 l2[4][4], a02[4][4], a12[4][4];  // [r][h]
#pragma unroll
  for (int r = 0; r < 4; ++r)
#pragma unroll
    for (int h = 0; h < 4; ++h) {
      l2[r][h] = (vf2)(0.0f);
      a02[r][h] = (vf2)(0.0f);
      a12[r][h] = (vf2)(0.0f);
    }

  const float* adjk = adj + (size_t)k * NN * NN;
  const int jw = wave * 1024 + lane * 4;

#pragma unroll 1
  for (int t = 0; t < 4; ++t) {
    const int j = jw + t * 256;
    vf4 av[4];
#pragma unroll
    for (int r = 0; r < 4; ++r)
      av[r] = *(const vf4*)(adjk + (size_t)(r0 + r) * NN + j);
#pragma unroll
    for (int h = 0; h < 4; ++h) {
      const size_t pb = (size_t)(k * HH + h) * NN + j;
      vf4 b = *(const vf4*)(Bp + pb);
      vf4 b5 = *(const vf4*)(B5p + pb);
      vf4 g0 = *(const vf4*)(g0p + pb);
      vf4 g1 = *(const vf4*)(g1p + pb);
      vf2 blo = {b.x, b.y}, bhi = {b.z, b.w};
      vf2 b5lo = {b5.x, b5.y}, b5hi = {b5.z, b5.w};
      vf2 g0lo = {g0.x, g0.y}, g0hi = {g0.z, g0.w};
      vf2 g1lo = {g1.x, g1.y}, g1hi = {g1.z, g1.w};
#pragma unroll
      for (int r = 0; r < 4; ++r) {
        vf2 alo = {av[r].x, av[r].y}, ahi = {av[r].z, av[r].w};
        {
          vf2 e = __builtin_elementwise_max(blo * A[r][h], b5lo * A5[r][h]);
          vf2 pa = e * alo;
          l2[r][h] += pa;
          a02[r][h] = __builtin_elementwise_fma(pa, g0lo, a02[r][h]);
          a12[r][h] = __builtin_elementwise_fma(pa, g1lo, a12[r][h]);
        }
        {
          vf2 e = __builtin_elementwise_max(bhi * A[r][h], b5hi * A5[r][h]);
          vf2 pa = e * ahi;
          l2[r][h] += pa;
          a02[r][h] = __builtin_elementwise_fma(pa, g0hi, a02[r][h]);
          a12[r][h] = __builtin_elementwise_fma(pa, g1hi, a12[r][h]);
        }
      }
    }
  }

  // fold vf2 -> scalar, butterfly across 64 lanes (48 values)
  float red[4][4][3];
#pragma unroll
  for (int r = 0; r < 4; ++r)
#pragma unroll
    for (int h = 0; h < 4; ++h) {
      float x0 = l2[r][h].x + l2[r][h].y;
      float x1 = a02[r][h].x + a02[r][h].y;
      float x2 = a12[r][h].x + a12[r][h].y;
#pragma unroll
      for (int off = 32; off > 0; off >>= 1) {
        x0 += __shfl_xor(x0, off, 64);
        x1 += __shfl_xor(x1, off, 64);
        x2 += __shfl_xor(x2, off, 64);
      }
      red[r][h][0] = x0;
      red[r][h][1] = x1;
      red[r][h][2] = x2;
    }

  __shared__ float sred[4][48];
  if (lane == 0) {
#pragma unroll
    for (int r = 0; r < 4; ++r)
#pragma unroll
      for (int h = 0; h < 4; ++h) {
#pragma unroll
        for (int c = 0; c < 3; ++c)
          sred[wave][(r * 4 + h) * 3 + c] = red[r][h][c];
      }
  }
  __syncthreads();
  if (tid < 8) {
    const int r = tid >> 1, c = tid & 1;
    float acc = 0.0f;
#pragma unroll
    for (int h = 0; h < 4; ++h) {
      const int vb = (r * 4 + h) * 3;
      float ls = sred[0][vb] + sred[1][vb] + sred[2][vb] + sred[3][vb];
      float ac = sred[0][vb + 1 + c] + sred[1][vb + 1 + c] +
                 sred[2][vb + 1 + c] + sred[3][vb + 1 + c];
      acc += ac / ls;
    }
    S[((size_t)k * NU + r0 + r) * CC + c] = 0.25f * acc;
  }
}

// ---------------------------------------------------------------------------
// Phase 3: sum kinds, +bias, log_softmax over C=2.
// ---------------------------------------------------------------------------
__global__ __launch_bounds__(256) void gat_phase3(
    const float* __restrict__ S, const float* __restrict__ fc_b,
    float* __restrict__ out) {
  const int i = blockIdx.x * 256 + threadIdx.x;
  if (i >= NU) return;
  float l0 = S[(size_t)i * CC + 0] + S[((size_t)NU + i) * CC + 0] + fc_b[0];
  float l1 = S[(size_t)i * CC + 1] + S[((size_t)NU + i) * CC + 1] + fc_b[1];
  float m = fmaxf(l0, l1);
  float lse = m + logf(expf(l0 - m) + expf(l1 - m));
  out[i * CC + 0] = l0 - lse;
  out[i * CC + 1] = l1 - lse;
}

extern "C" void kernel_launch(void* const* d_in, const int* in_sizes, int n_in,
                              void* d_out, int out_size, void* d_ws, size_t ws_size,
                              hipStream_t stream) {
  const float* hsrc  = (const float*)d_in[0];  // (1,4096,64)
  const float* hadj  = (const float*)d_in[1];  // (2,1,4096,4096)
  const float* w     = (const float*)d_in[2];  // (2,4,64,64)
  const float* a_src = (const float*)d_in[3];  // (2,4,64,1)
  const float* a_dst = (const float*)d_in[4];  // (2,4,64,1)
  const float* fc_w  = (const float*)d_in[5];  // (2,128)
  const float* fc_b  = (const float*)d_in[6];  // (2,)
  float* out = (float*)d_out;                  // (1,4000,2) fp32

  char* ws = (char*)d_ws;
  float* srcAA = (float*)(ws + 0);        // K*H*N*2 (256 KB)
  float* Bp    = (float*)(ws + 262144);   // K*H*N   (128 KB)
  float* B5p   = (float*)(ws + 393216);
  float* g0p   = (float*)(ws + 524288);
  float* g1p   = (float*)(ws + 655360);
  float* S     = (float*)(ws + 786432);   // K*NU*C  (64 KB)

  dim3 g1(NN / 64, KK * HH);
  gat_phase1<<<g1, 256, 0, stream>>>(hsrc, w, a_src, a_dst, fc_w,
                                     srcAA, Bp, B5p, g0p, g1p);
  dim3 g2(NU / 4, KK);
  gat_phase2<<<g2, 256, 0, stream>>>(hadj, srcAA, Bp, B5p, g0p, g1p, S);
  gat_phase3<<<(NU + 255) / 256, 256, 0, stream>>>(S, fc_b, out);
}